// Round 1
// 633.438 us; speedup vs baseline: 1.0003x; 1.0003x over previous
//
#include <hip/hip_runtime.h>

#define BB 8
#define NN 4096
#define FF 128
#define GS 1024

// ---------------------------------------------------------------------------
// Kernel 1: build sortable keys + zero the rank counters.
// key = (~sortable_asc(v) << 32) | i  -> ascending 64-bit key order ==
// descending value with ascending-index tie-break (exact jax.lax.top_k
// semantics). Keys are all distinct (index in low bits).
// Counters must be zeroed every call (harness poisons d_ws with 0xAA).
// ---------------------------------------------------------------------------
__global__ __launch_bounds__(256) void keys_kernel(const float* __restrict__ x,
                                                   unsigned long long* __restrict__ keys,
                                                   int* __restrict__ cnt) {
    int gid = blockIdx.x * 256 + threadIdx.x;      // [0, BB*NN)
    int b = gid >> 12;
    int i = gid & (NN - 1);
    float v = x[((size_t)b * NN + i) * FF + (FF - 1)];
    unsigned int bits = __float_as_uint(v);
    unsigned int sv = (bits & 0x80000000u) ? ~bits : (bits | 0x80000000u);
    keys[gid] = ((unsigned long long)(~sv) << 32) | (unsigned int)i;
    cnt[gid] = 0;
}

// ---------------------------------------------------------------------------
// Kernel 2: partial rank counts (unchanged — modeled ~5 us).
// Grid = 8 batches x 4 elem-chunks(1024) x 8 key-chunks(512) = 256 blocks.
// LDS broadcast ds_read_b128, atomicAdd partials (no contention).
// ---------------------------------------------------------------------------
__global__ __launch_bounds__(256) void rank_part_kernel(const unsigned long long* __restrict__ keys,
                                                        int* __restrict__ cnt) {
    __shared__ unsigned long long lk[512];         // 4 KB
    const int b  = blockIdx.x >> 5;                // batch
    const int ec = (blockIdx.x >> 3) & 3;          // element chunk (1024 elems)
    const int kc = blockIdx.x & 7;                 // key chunk (512 keys)
    const unsigned long long* kb = keys + ((size_t)b << 12);

    const ulonglong2* g2 = (const ulonglong2*)(kb + (kc << 9));
    ulonglong2*       l2 = (ulonglong2*)lk;
    l2[threadIdx.x] = g2[threadIdx.x];             // 256 threads x 16B = 4 KB

    const int e0 = (ec << 10) + threadIdx.x;
    unsigned long long m0 = kb[e0];
    unsigned long long m1 = kb[e0 + 256];
    unsigned long long m2 = kb[e0 + 512];
    unsigned long long m3 = kb[e0 + 768];
    __syncthreads();

    int c0 = 0, c1 = 0, c2 = 0, c3 = 0;
#pragma unroll 4
    for (int s = 0; s < 256; ++s) {
        ulonglong2 kk = l2[s];                     // broadcast b128
        c0 += (kk.x < m0) + (kk.y < m0);
        c1 += (kk.x < m1) + (kk.y < m1);
        c2 += (kk.x < m2) + (kk.y < m2);
        c3 += (kk.x < m3) + (kk.y < m3);
    }
    int* cb = cnt + ((size_t)b << 12);
    atomicAdd(&cb[e0],       c0);
    atomicAdd(&cb[e0 + 256], c1);
    atomicAdd(&cb[e0 + 512], c2);
    atomicAdd(&cb[e0 + 768], c3);
}

// ---------------------------------------------------------------------------
// Kernel 3: finalize (unchanged). rank < GS -> exact output slot.
// ---------------------------------------------------------------------------
__global__ __launch_bounds__(256) void finalize_kernel(const int* __restrict__ cnt,
                                                       int* __restrict__ idx) {
    int gid = blockIdx.x * 256 + threadIdx.x;      // [0, BB*NN)
    int b = gid >> 12;
    int i = gid & (NN - 1);
    int c = cnt[gid];
    if (c < GS) idx[(b << 10) + c] = i;
}

// ---------------------------------------------------------------------------
// Kernel 4 (REBUILT): 2 output rows per block, 512 threads, 32 KB LDS.
//  - Row staging via __builtin_amdgcn_global_load_lds width=16: each wave
//    call moves 1 KB HBM->LDS with no VGPR round-trip. LDS dest is
//    wave-uniform base + lane*16 (linear layout, required by HW); global
//    src is per-lane. chunk = w*64 + k*512 is wave-uniform; the 64-lane
//    span never crosses the row0/row1 boundary (multiples of 64).
//  - Column indices: each thread loads its own int4 from L2-resident idx
//    (coalesced, 16 B/lane) -- no cols[] LDS, no second staging loop.
//  - 4 blocks/CU (32 KB LDS, 512 thr) = 2048 threads/CU, 128 KB HBM
//    reads in flight per CU.
// ---------------------------------------------------------------------------
__global__ __launch_bounds__(512) void gatherAx_kernel(const float* __restrict__ A,
                                                       const float* __restrict__ x,
                                                       const int* __restrict__ idx,
                                                       float* __restrict__ outA,
                                                       float* __restrict__ outx) {
    __shared__ float rows[2 * NN];                 // 32 KB: row0 | row1
    const int b  = blockIdx.x >> 9;                // batch
    const int jp = blockIdx.x & 511;               // output-row pair
    const int* idxb = idx + (b << 10);
    const int s0 = idxb[2 * jp];
    const int s1 = idxb[2 * jp + 1];
    const float* r0 = A + ((size_t)b * NN + s0) * NN;
    const float* r1 = A + ((size_t)b * NN + s1) * NN;

    const int w = threadIdx.x >> 6;                // wave id [0,8)
    const int l = threadIdx.x & 63;                // lane
#pragma unroll
    for (int k = 0; k < 4; ++k) {
        const int chunk = w * 64 + k * 512;        // wave-uniform 16B-chunk base
        const int c = chunk + l;                   // per-lane chunk id [0,2048)
        const float* g = (c < 1024) ? (r0 + (c << 2)) : (r1 + ((c - 1024) << 2));
        __builtin_amdgcn_global_load_lds(
            (const __attribute__((address_space(1))) void*)g,
            (__attribute__((address_space(3))) void*)&rows[chunk << 2],
            16, 0, 0);
    }

    // fused x gather: wave 0 moves 2 rows x 128 floats (32 lanes x float4 each)
    if (threadIdx.x < 64) {
        const int rr = threadIdx.x >> 5, ll = threadIdx.x & 31;
        const int sr = rr ? s1 : s0;
        const float4* s4 = (const float4*)(x + ((size_t)b * NN + sr) * FF);
        float4*       d4 = (float4*)(outx + ((size_t)((b << 10) + 2 * jp + rr)) * FF);
        d4[ll] = s4[ll];
    }
    __syncthreads();                               // drains vmcnt -> LDS valid

    const int r = threadIdx.x >> 8;                // which row of the pair
    const int i = threadIdx.x & 255;               // output quad index
    const int4 c4 = ((const int4*)idxb)[i];        // own 4 column indices (L2)
    const float* rowp = rows + (r << 12);
    float4 v;
    v.x = rowp[c4.x];
    v.y = rowp[c4.y];
    v.z = rowp[c4.z];
    v.w = rowp[c4.w];
    float4* out4 = (float4*)(outA + ((size_t)((b << 10) + 2 * jp + r)) * GS);
    out4[i] = v;
}

extern "C" void kernel_launch(void* const* d_in, const int* in_sizes, int n_in,
                              void* d_out, int out_size, void* d_ws, size_t ws_size,
                              hipStream_t stream) {
    const float* A = (const float*)d_in[0];   // (8, 4096, 4096) fp32
    const float* x = (const float*)d_in[1];   // (8, 4096, 128)  fp32

    float* outA = (float*)d_out;                          // (8, 1024, 1024)
    float* outx = outA + (size_t)BB * GS * GS;            // (8, 1024, 128)

    int* idx = (int*)d_ws;                                              // 32 KB
    unsigned long long* keys = (unsigned long long*)((char*)d_ws + (64 << 10));   // 256 KB
    int* cnt = (int*)((char*)d_ws + (512 << 10));                       // 128 KB

    keys_kernel<<<(BB * NN) / 256, 256, 0, stream>>>(x, keys, cnt);
    rank_part_kernel<<<256, 256, 0, stream>>>(keys, cnt);
    finalize_kernel<<<(BB * NN) / 256, 256, 0, stream>>>(cnt, idx);
    gatherAx_kernel<<<(BB * GS) / 2, 512, 0, stream>>>(A, x, idx, outA, outx);
}